// Round 6
// baseline (508.677 us; speedup 1.0000x reference)
//
#include <hip/hip_runtime.h>

typedef __bf16 bf16;
typedef __bf16 bf16x4 __attribute__((ext_vector_type(4)));
typedef __bf16 bf16x8 __attribute__((ext_vector_type(8)));
typedef float  f32x4  __attribute__((ext_vector_type(4)));

#define B_ 2048
#define T_ 128
#define C_ 256
#define H_ 64

// LDS layout (bytes), shrunk strides for 3 blocks/CU:
//  Qs[128][68] @0     (17408)
//  Ks[128][68] @17408 (17408)
//  Vt[64][132] @34816 (16896)  -> high-water 51712
//  Ps[128][132] @0    (33792)  aliases Qs + most of Ks after S-phase reads done
// 3 * 51712 = 155136 <= 163840 (8.5 KB slack for driver reserve) -> 12 waves/CU
// Register cap fix: proj split into two nt-passes (acc[2][6] = 48 regs, not 96),
// so total VGPR+AGPR stays < 170 -> 3 waves/SIMD permitted.
#define LDQ 68
#define LDV 132
#define SMEM_BYTES 51712

__global__ void wt_kernel(const float* __restrict__ Wk, const float* __restrict__ Wq,
                          const float* __restrict__ Wv, bf16* __restrict__ Wt) {
    int o = blockIdx.x * 256 + threadIdx.x;     // 0..49151
    int slot = o >> 14;
    int r    = o & 16383;                       // coalesced source read
    int cc   = r >> 6;
    int h    = r & 63;
    const float* src = (slot == 0) ? Wq : (slot == 1 ? Wk : Wv);
    Wt[slot * 16384 + h * 256 + cc] = (bf16)src[r];
}

__global__ void __launch_bounds__(256, 3)
attn_kernel(const float* __restrict__ xg, const bf16* __restrict__ Wt,
            float* __restrict__ outg) {
    __shared__ __align__(16) char smem_raw[SMEM_BYTES];
    bf16* Qs  = (bf16*)smem_raw;                 // [128][68]
    bf16* Ks  = (bf16*)(smem_raw + 17408);       // [128][68]
    bf16* Vt  = (bf16*)(smem_raw + 34816);       // [64][132]
    bf16* Ps  = (bf16*)smem_raw;                 // [128][132]

    const int tid  = threadIdx.x;
    const int b    = blockIdx.x;
    const int w    = tid >> 6;
    const int lane = tid & 63;
    const int quad = lane >> 4;
    const int n16  = lane & 15;

    const f32x4 zero4 = {0.f, 0.f, 0.f, 0.f};
    const float*  xbp = xg + (size_t)b * (T_ * C_);
    const ushort* WtU = (const ushort*)Wt;

    // ---------------- projections: two nt-passes, 2-deep x register pipeline ----------------
    // pass p covers global nt = 6p..6p+5 (nt 0..3 = Q, 4..7 = K, 8..11 = V)
    const float* xr0 = xbp + (32 * w + n16) * C_ + 8 * quad;       // rows of mt=0 tile
    const float* xr1 = xr0 + 16 * C_;                              // rows of mt=1 tile

    #pragma unroll
    for (int pass = 0; pass < 2; pass++) {
        f32x4 acc[2][6];
        #pragma unroll
        for (int mt = 0; mt < 2; mt++)
            #pragma unroll
            for (int nt = 0; nt < 6; nt++) acc[mt][nt] = zero4;

        float4 c00 = *(const float4*)(xr0);
        float4 c01 = *(const float4*)(xr0 + 4);
        float4 c10 = *(const float4*)(xr1);
        float4 c11 = *(const float4*)(xr1 + 4);

        #pragma unroll
        for (int ks = 0; ks < 8; ks++) {
            float4 n00, n01, n10, n11;
            if (ks < 7) {                        // prefetch next ks (static guard)
                n00 = *(const float4*)(xr0 + (ks + 1) * 32);
                n01 = *(const float4*)(xr0 + (ks + 1) * 32 + 4);
                n10 = *(const float4*)(xr1 + (ks + 1) * 32);
                n11 = *(const float4*)(xr1 + (ks + 1) * 32 + 4);
            }
            bf16x8 a0 = {(bf16)c00.x, (bf16)c00.y, (bf16)c00.z, (bf16)c00.w,
                         (bf16)c01.x, (bf16)c01.y, (bf16)c01.z, (bf16)c01.w};
            bf16x8 a1 = {(bf16)c10.x, (bf16)c10.y, (bf16)c10.z, (bf16)c10.w,
                         (bf16)c11.x, (bf16)c11.y, (bf16)c11.z, (bf16)c11.w};
            #pragma unroll
            for (int nt = 0; nt < 6; nt++) {
                int ntg = pass * 6 + nt;
                // B-fragments from global Wt (96 KB, L2-resident, shared by all blocks)
                const ushort* wp = WtU + (ntg >> 2) * 16384 + (16 * (ntg & 3) + n16) * 256 + ks * 32 + 8 * quad;
                bf16x8 bfr = *(const bf16x8*)wp;
                acc[0][nt] = __builtin_amdgcn_mfma_f32_16x16x32_bf16(a0, bfr, acc[0][nt], 0, 0, 0);
                acc[1][nt] = __builtin_amdgcn_mfma_f32_16x16x32_bf16(a1, bfr, acc[1][nt], 0, 0, 0);
            }
            if (ks < 7) { c00 = n00; c01 = n01; c10 = n10; c11 = n11; }
        }

        // write this pass's outputs: Q (pre-scaled by C^-0.5 = 2^-4, exact), K, Vt
        #pragma unroll
        for (int mt = 0; mt < 2; mt++) {
            int tbase = 16 * (2 * w + mt) + 4 * quad;
            #pragma unroll
            for (int nt = 0; nt < 6; nt++) {
                int ntg = pass * 6 + nt;
                if (ntg < 4) {                   // Q, scaled
                    int h = 16 * ntg + n16;
                    #pragma unroll
                    for (int r = 0; r < 4; r++)
                        Qs[(tbase + r) * LDQ + h] = (bf16)(acc[mt][nt][r] * 0.0625f);
                } else if (ntg < 8) {            // K
                    int h = 16 * (ntg - 4) + n16;
                    #pragma unroll
                    for (int r = 0; r < 4; r++)
                        Ks[(tbase + r) * LDQ + h] = (bf16)acc[mt][nt][r];
                } else {                         // V transposed: Vt[h][t]
                    int h = 16 * (ntg - 8) + n16;
                    bf16x4 pv = {(bf16)acc[mt][nt][0], (bf16)acc[mt][nt][1],
                                 (bf16)acc[mt][nt][2], (bf16)acc[mt][nt][3]};
                    *(bf16x4*)(Vt + h * LDV + tbase) = pv;
                }
            }
        }
    }
    __syncthreads();                             // (1) Q/K/V visible to all waves

    // ---------------- S = Q K^T, causal softmax ----------------
    f32x4 sacc[2][8];
    int mts[2] = {w, 7 - w};
    #pragma unroll
    for (int half = 0; half < 2; half++) {
        int mt = mts[half];
        int sT = ((mt >> 1) + 1) * 2;
        bf16x8 qa[2];
        #pragma unroll
        for (int ks = 0; ks < 2; ks++)
            qa[ks] = *(const bf16x8*)(Qs + (16 * mt + n16) * LDQ + 32 * ks + 8 * quad);
        #pragma unroll
        for (int nt = 0; nt < 8; nt++) {
            sacc[half][nt] = zero4;
            if (nt < sT) {
                bf16x8 kb0 = *(const bf16x8*)(Ks + (16 * nt + n16) * LDQ + 8 * quad);
                bf16x8 kb1 = *(const bf16x8*)(Ks + (16 * nt + n16) * LDQ + 32 + 8 * quad);
                sacc[half][nt] = __builtin_amdgcn_mfma_f32_16x16x32_bf16(qa[0], kb0, sacc[half][nt], 0, 0, 0);
                sacc[half][nt] = __builtin_amdgcn_mfma_f32_16x16x32_bf16(qa[1], kb1, sacc[half][nt], 0, 0, 0);
            }
        }
        #pragma unroll
        for (int r = 0; r < 4; r++) {
            int t = 16 * mt + 4 * quad + r;
            float mx = -3.0e38f;
            #pragma unroll
            for (int nt = 0; nt < 8; nt++) {
                if (nt < sT) {
                    float v = sacc[half][nt][r];                 // already C^-0.5-scaled
                    v = (16 * nt + n16 <= t) ? v : -3.0e38f;     // causal
                    sacc[half][nt][r] = v;
                    mx = fmaxf(mx, v);
                }
            }
            mx = fmaxf(mx, __shfl_xor(mx, 1));
            mx = fmaxf(mx, __shfl_xor(mx, 2));
            mx = fmaxf(mx, __shfl_xor(mx, 4));
            mx = fmaxf(mx, __shfl_xor(mx, 8));
            float sum = 0.f;
            #pragma unroll
            for (int nt = 0; nt < 8; nt++) {
                if (nt < sT) {
                    float p = __builtin_amdgcn_exp2f((sacc[half][nt][r] - mx) * 1.4426950408889634f);
                    sacc[half][nt][r] = p;
                    sum += p;
                }
            }
            sum += __shfl_xor(sum, 1);
            sum += __shfl_xor(sum, 2);
            sum += __shfl_xor(sum, 4);
            sum += __shfl_xor(sum, 8);
            float rinv = 1.0f / sum;
            #pragma unroll
            for (int nt = 0; nt < 8; nt++)
                if (nt < sT) sacc[half][nt][r] *= rinv;
        }
    }
    __syncthreads();                             // (2) all Q/K reads done; Ps may alias

    #pragma unroll
    for (int half = 0; half < 2; half++) {
        int mt = mts[half];
        int sT = ((mt >> 1) + 1) * 2;
        #pragma unroll
        for (int nt = 0; nt < 8; nt++) {
            if (nt < sT) {
                #pragma unroll
                for (int r = 0; r < 4; r++)
                    Ps[(16 * mt + 4 * quad + r) * LDV + 16 * nt + n16] = (bf16)sacc[half][nt][r];
            }
        }
    }
    __syncthreads();                             // (3) Ps visible

    // ---------------- O = P V, per-half (oacc[4] reused), direct global store ----------------
    #pragma unroll
    for (int half = 0; half < 2; half++) {
        int mt  = mts[half];
        int kst = (mt >> 1) + 1;
        f32x4 oacc[4];
        #pragma unroll
        for (int nt = 0; nt < 4; nt++) oacc[nt] = zero4;
        #pragma unroll
        for (int ks = 0; ks < 4; ks++) {
            if (ks < kst) {
                bf16x8 pa = *(const bf16x8*)(Ps + (16 * mt + n16) * LDV + 32 * ks + 8 * quad);
                #pragma unroll
                for (int nt = 0; nt < 4; nt++) {
                    bf16x8 vb = *(const bf16x8*)(Vt + (16 * nt + n16) * LDV + 32 * ks + 8 * quad);
                    oacc[nt] = __builtin_amdgcn_mfma_f32_16x16x32_bf16(pa, vb, oacc[nt], 0, 0, 0);
                }
            }
        }
        // r-outer ordering: each output row's two 128B lines complete in
        // consecutive stores -> L2 write-combining (targets WRITE_SIZE bloat)
        float* ob = outg + ((size_t)b * T_ + 16 * mt + 4 * quad) * H_;
        #pragma unroll
        for (int r = 0; r < 4; r++)
            #pragma unroll
            for (int nt = 0; nt < 4; nt++)
                ob[r * H_ + 16 * nt + n16] = oacc[nt][r];
    }
}

extern "C" void kernel_launch(void* const* d_in, const int* in_sizes, int n_in,
                              void* d_out, int out_size, void* d_ws, size_t ws_size,
                              hipStream_t stream) {
    const float* x  = (const float*)d_in[0];
    const float* Wk = (const float*)d_in[1];
    const float* Wq = (const float*)d_in[2];
    const float* Wv = (const float*)d_in[3];
    bf16* Wt = (bf16*)d_ws;                      // 98304 B scratch
    wt_kernel<<<192, 256, 0, stream>>>(Wk, Wq, Wv, Wt);
    attn_kernel<<<B_, 256, 0, stream>>>(x, Wt, (float*)d_out);
}

// Round 7
// 433.828 us; speedup vs baseline: 1.1725x; 1.1725x over previous
//
#include <hip/hip_runtime.h>

typedef __bf16 bf16;
typedef __bf16 bf16x4 __attribute__((ext_vector_type(4)));
typedef __bf16 bf16x8 __attribute__((ext_vector_type(8)));
typedef float  f32x4  __attribute__((ext_vector_type(4)));

#define B_ 2048
#define T_ 128
#define C_ 256
#define H_ 64

// LDS layout (bytes):
//  phase0/1: xs[128][264] bf16 @0 = 67584 (whole x tile, stride 264: rows 8 apart
//            alias banks -> 2-way, free per m136)
//  phase2:   Qs[128][68] @0 (17408), Ks[128][68] @17408, Vt[64][132] @34816 (16896)
//  phase3:   Ps[128][132] @0 (33792) — all alias xs (dead after proj MFMAs)
// high-water 67584 * 2 blocks = 135168 <= 163840 -> 2 blocks/CU (8 waves/CU).
// Occupancy deliberately NOT chased (r5/r6 falsified it); this round attacks the
// proj-phase L2-load chain: wave owns an nt-SLICE (3 tiles) x all 8 row-tiles,
// so each Wt fragment is loaded once and reused 8x (24 L2 loads/wave, was 96).
#define LDX 264
#define LDQ 68
#define LDV 132
#define SMEM_BYTES 67584

__global__ void wt_kernel(const float* __restrict__ Wk, const float* __restrict__ Wq,
                          const float* __restrict__ Wv, bf16* __restrict__ Wt) {
    int o = blockIdx.x * 256 + threadIdx.x;     // 0..49151
    int slot = o >> 14;
    int r    = o & 16383;                       // coalesced source read
    int cc   = r >> 6;
    int h    = r & 63;
    const float* src = (slot == 0) ? Wq : (slot == 1 ? Wk : Wv);
    Wt[slot * 16384 + h * 256 + cc] = (bf16)src[r];
}

__global__ void __launch_bounds__(256, 2)
attn_kernel(const float* __restrict__ xg, const bf16* __restrict__ Wt,
            float* __restrict__ outg) {
    __shared__ __align__(16) char smem_raw[SMEM_BYTES];
    bf16* xs  = (bf16*)smem_raw;                 // [128][264]
    bf16* Qs  = (bf16*)smem_raw;                 // [128][68]
    bf16* Ks  = (bf16*)(smem_raw + 17408);       // [128][68]
    bf16* Vt  = (bf16*)(smem_raw + 34816);       // [64][132]
    bf16* Ps  = (bf16*)smem_raw;                 // [128][132]

    const int tid  = threadIdx.x;
    const int b    = blockIdx.x;
    const int w    = tid >> 6;
    const int lane = tid & 63;
    const int quad = lane >> 4;
    const int n16  = lane & 15;

    const f32x4 zero4 = {0.f, 0.f, 0.f, 0.f};
    const float*  xbp = xg + (size_t)b * (T_ * C_);
    const ushort* WtU = (const ushort*)Wt;

    // ---------------- phase 0: stage ALL of x (fp32->bf16), 2-deep pipelined ----------------
    // (verbatim from the 210us baseline: bulk coalesced, x fetched exactly once)
    {
        float4 xa[8], xb4[8];
        #pragma unroll
        for (int i = 0; i < 8; i++) {
            int f = i * 256 + tid;
            xa[i] = *(const float4*)(xbp + (f >> 6) * C_ + (f & 63) * 4);
        }
        #pragma unroll
        for (int g = 0; g < 4; g++) {
            float4* cur = (g & 1) ? xb4 : xa;
            float4* nxt = (g & 1) ? xa : xb4;
            if (g < 3) {
                #pragma unroll
                for (int i = 0; i < 8; i++) {
                    int f = (g + 1) * 2048 + i * 256 + tid;
                    nxt[i] = *(const float4*)(xbp + (f >> 6) * C_ + (f & 63) * 4);
                }
            }
            #pragma unroll
            for (int i = 0; i < 8; i++) {
                int f = g * 2048 + i * 256 + tid;
                int t = f >> 6, c4 = (f & 63) * 4;
                bf16x4 bv = {(bf16)cur[i].x, (bf16)cur[i].y, (bf16)cur[i].z, (bf16)cur[i].w};
                *(bf16x4*)(xs + t * LDX + c4) = bv;
            }
        }
    }
    __syncthreads();                             // (1) xs visible

    // ---------------- phase 1: projections, nt-sliced: wave w -> nt tiles 3w..3w+2 ----------------
    // Per wave: 24 Wt L2 loads (was 96), 64 ds_read_b128 A-frags, 192 MFMA.
    const int w3 = 3 * w;
    const ushort* wb0 = WtU + ((w3 + 0) >> 2) * 16384 + (16 * ((w3 + 0) & 3) + n16) * 256 + 8 * quad;
    const ushort* wb1 = WtU + ((w3 + 1) >> 2) * 16384 + (16 * ((w3 + 1) & 3) + n16) * 256 + 8 * quad;
    const ushort* wb2 = WtU + ((w3 + 2) >> 2) * 16384 + (16 * ((w3 + 2) & 3) + n16) * 256 + 8 * quad;

    f32x4 acc[8][3];
    #pragma unroll
    for (int mt = 0; mt < 8; mt++)
        #pragma unroll
        for (int j = 0; j < 3; j++) acc[mt][j] = zero4;

    #pragma unroll
    for (int ks = 0; ks < 8; ks++) {
        bf16x8 b0 = *(const bf16x8*)(wb0 + ks * 32);
        bf16x8 b1 = *(const bf16x8*)(wb1 + ks * 32);
        bf16x8 b2 = *(const bf16x8*)(wb2 + ks * 32);
        #pragma unroll
        for (int mt = 0; mt < 8; mt++) {
            bf16x8 a = *(const bf16x8*)(xs + (16 * mt + n16) * LDX + ks * 32 + 8 * quad);
            acc[mt][0] = __builtin_amdgcn_mfma_f32_16x16x32_bf16(a, b0, acc[mt][0], 0, 0, 0);
            acc[mt][1] = __builtin_amdgcn_mfma_f32_16x16x32_bf16(a, b1, acc[mt][1], 0, 0, 0);
            acc[mt][2] = __builtin_amdgcn_mfma_f32_16x16x32_bf16(a, b2, acc[mt][2], 0, 0, 0);
        }
    }
    __syncthreads();                             // (2) all xs reads done; Q/K/V may alias

    // write Q[t][h] (pre-scaled by C^-0.5 = 2^-4, exact in bf16), K[s][h], Vt[h][t]
    // branches are wave-uniform (w): each wave writes all 128 rows of its 3 h-slices
    #pragma unroll
    for (int j = 0; j < 3; j++) {
        int ng = w3 + j;
        if (ng < 4) {                            // Q, scaled
            int h = 16 * ng + n16;
            #pragma unroll
            for (int mt = 0; mt < 8; mt++) {
                int tbase = 16 * mt + 4 * quad;
                #pragma unroll
                for (int r = 0; r < 4; r++)
                    Qs[(tbase + r) * LDQ + h] = (bf16)(acc[mt][j][r] * 0.0625f);
            }
        } else if (ng < 8) {                     // K
            int h = 16 * (ng - 4) + n16;
            #pragma unroll
            for (int mt = 0; mt < 8; mt++) {
                int tbase = 16 * mt + 4 * quad;
                #pragma unroll
                for (int r = 0; r < 4; r++)
                    Ks[(tbase + r) * LDQ + h] = (bf16)acc[mt][j][r];
            }
        } else {                                 // V transposed: Vt[h][t]
            int h = 16 * (ng - 8) + n16;
            #pragma unroll
            for (int mt = 0; mt < 8; mt++) {
                bf16x4 pv = {(bf16)acc[mt][j][0], (bf16)acc[mt][j][1],
                             (bf16)acc[mt][j][2], (bf16)acc[mt][j][3]};
                *(bf16x4*)(Vt + h * LDV + 16 * mt + 4 * quad) = pv;
            }
        }
    }
    __syncthreads();                             // (3) Q/K/V visible to all waves

    // ---------------- S = Q K^T, causal softmax (verbatim from r6: 0 bank conflicts) ----------------
    f32x4 sacc[2][8];
    int mts[2] = {w, 7 - w};
    #pragma unroll
    for (int half = 0; half < 2; half++) {
        int mt = mts[half];
        int sT = ((mt >> 1) + 1) * 2;
        bf16x8 qa[2];
        #pragma unroll
        for (int ks = 0; ks < 2; ks++)
            qa[ks] = *(const bf16x8*)(Qs + (16 * mt + n16) * LDQ + 32 * ks + 8 * quad);
        #pragma unroll
        for (int nt = 0; nt < 8; nt++) {
            sacc[half][nt] = zero4;
            if (nt < sT) {
                bf16x8 kb0 = *(const bf16x8*)(Ks + (16 * nt + n16) * LDQ + 8 * quad);
                bf16x8 kb1 = *(const bf16x8*)(Ks + (16 * nt + n16) * LDQ + 32 + 8 * quad);
                sacc[half][nt] = __builtin_amdgcn_mfma_f32_16x16x32_bf16(qa[0], kb0, sacc[half][nt], 0, 0, 0);
                sacc[half][nt] = __builtin_amdgcn_mfma_f32_16x16x32_bf16(qa[1], kb1, sacc[half][nt], 0, 0, 0);
            }
        }
        #pragma unroll
        for (int r = 0; r < 4; r++) {
            int t = 16 * mt + 4 * quad + r;
            float mx = -3.0e38f;
            #pragma unroll
            for (int nt = 0; nt < 8; nt++) {
                if (nt < sT) {
                    float v = sacc[half][nt][r];                 // already C^-0.5-scaled
                    v = (16 * nt + n16 <= t) ? v : -3.0e38f;     // causal
                    sacc[half][nt][r] = v;
                    mx = fmaxf(mx, v);
                }
            }
            mx = fmaxf(mx, __shfl_xor(mx, 1));
            mx = fmaxf(mx, __shfl_xor(mx, 2));
            mx = fmaxf(mx, __shfl_xor(mx, 4));
            mx = fmaxf(mx, __shfl_xor(mx, 8));
            float sum = 0.f;
            #pragma unroll
            for (int nt = 0; nt < 8; nt++) {
                if (nt < sT) {
                    float p = __builtin_amdgcn_exp2f((sacc[half][nt][r] - mx) * 1.4426950408889634f);
                    sacc[half][nt][r] = p;
                    sum += p;
                }
            }
            sum += __shfl_xor(sum, 1);
            sum += __shfl_xor(sum, 2);
            sum += __shfl_xor(sum, 4);
            sum += __shfl_xor(sum, 8);
            float rinv = 1.0f / sum;
            #pragma unroll
            for (int nt = 0; nt < 8; nt++)
                if (nt < sT) sacc[half][nt][r] *= rinv;
        }
    }
    __syncthreads();                             // (4) all Q/K reads done; Ps may alias

    #pragma unroll
    for (int half = 0; half < 2; half++) {
        int mt = mts[half];
        int sT = ((mt >> 1) + 1) * 2;
        #pragma unroll
        for (int nt = 0; nt < 8; nt++) {
            if (nt < sT) {
                #pragma unroll
                for (int r = 0; r < 4; r++)
                    Ps[(16 * mt + 4 * quad + r) * LDV + 16 * nt + n16] = (bf16)sacc[half][nt][r];
            }
        }
    }
    __syncthreads();                             // (5) Ps visible

    // ---------------- O = P V, direct global store (r-outer: clean WRITE_SIZE per r6) ----------------
    #pragma unroll
    for (int half = 0; half < 2; half++) {
        int mt  = mts[half];
        int kst = (mt >> 1) + 1;
        f32x4 oacc[4];
        #pragma unroll
        for (int nt = 0; nt < 4; nt++) oacc[nt] = zero4;
        #pragma unroll
        for (int ks = 0; ks < 4; ks++) {
            if (ks < kst) {
                bf16x8 pa = *(const bf16x8*)(Ps + (16 * mt + n16) * LDV + 32 * ks + 8 * quad);
                #pragma unroll
                for (int nt = 0; nt < 4; nt++) {
                    bf16x8 vb = *(const bf16x8*)(Vt + (16 * nt + n16) * LDV + 32 * ks + 8 * quad);
                    oacc[nt] = __builtin_amdgcn_mfma_f32_16x16x32_bf16(pa, vb, oacc[nt], 0, 0, 0);
                }
            }
        }
        float* ob = outg + ((size_t)b * T_ + 16 * mt + 4 * quad) * H_;
        #pragma unroll
        for (int r = 0; r < 4; r++)
            #pragma unroll
            for (int nt = 0; nt < 4; nt++)
                ob[r * H_ + 16 * nt + n16] = oacc[nt][r];
    }
}

extern "C" void kernel_launch(void* const* d_in, const int* in_sizes, int n_in,
                              void* d_out, int out_size, void* d_ws, size_t ws_size,
                              hipStream_t stream) {
    const float* x  = (const float*)d_in[0];
    const float* Wk = (const float*)d_in[1];
    const float* Wq = (const float*)d_in[2];
    const float* Wv = (const float*)d_in[3];
    bf16* Wt = (bf16*)d_ws;                      // 98304 B scratch
    wt_kernel<<<192, 256, 0, stream>>>(Wk, Wq, Wv, Wt);
    attn_kernel<<<B_, 256, 0, stream>>>(x, Wt, (float*)d_out);
}